// Round 5
// baseline (129.517 us; speedup 1.0000x reference)
//
#include <hip/hip_runtime.h>
#include <hip/hip_bf16.h>
#include <cstdint>
#include <cstddef>

typedef short bf16x8 __attribute__((ext_vector_type(8)));
typedef float f32x4 __attribute__((ext_vector_type(4)));
typedef float f32x16 __attribute__((ext_vector_type(16)));

#if __has_builtin(__builtin_amdgcn_exp2f)
#define EXP2F(x) __builtin_amdgcn_exp2f(x)
#else
#define EXP2F(x) exp2f(x)
#endif

// scale^2 * log2(e) folded into Q; ch=64 -> (1/8)*1.4426950408889634
#define QSCALE 0.18033688011112043f

__device__ __forceinline__ short f2bf(float f) {
  union { __hip_bfloat16 b; short s; } u;
  u.b = __float2bfloat16(f);
  return u.s;
}

__device__ __forceinline__ unsigned int bitsf(float f) {
  union { float f; unsigned int u; } x; x.f = f; return x.u;
}

// fast packed f32x2 -> bf16x2, round-half-up (values are finite positives:
// softmax P in [0, 256] after deferred-max; bias vs RNE <= 1 ulp on halves)
__device__ __forceinline__ unsigned int pkbf(float a, float b) {
  return ((bitsf(a) + 0x8000u) >> 16) | ((bitsf(b) + 0x8000u) & 0xFFFF0000u);
}

// ---------------------------------------------------------------------------
// Prepass: Kt[bh][s][c] = bf16(K[c][s]);  Vb[bh][c][s] = bf16(V[c][s]).
// qkv layout: [bh][cc][t], cc: 0..63 Q, 64..127 K, 128..191 V.
// ---------------------------------------------------------------------------
__global__ __launch_bounds__(256, 4) void qkv_prep_kernel(
    const float* __restrict__ qkv, short* __restrict__ Kt,
    short* __restrict__ Vb) {
  const int bh = blockIdx.x >> 5;
  const int s0 = (blockIdx.x & 31) << 6;
  const int tid = threadIdx.x;
  const int row = tid >> 2;   // 0..63
  const int part = tid & 3;   // 0..3  (16 columns each)
  __shared__ float lds[64 * 65];

  const size_t qb = (size_t)bh * (192 * 2048);

  // ---- K: load [c][s] tile coalesced into LDS ----
  {
    const float* src = qkv + qb + (size_t)(64 + row) * 2048 + s0 + part * 16;
#pragma unroll
    for (int k4 = 0; k4 < 4; ++k4) {
      float4 v = ((const float4*)src)[k4];
      float* p = &lds[row * 65 + part * 16 + k4 * 4];
      p[0] = v.x; p[1] = v.y; p[2] = v.z; p[3] = v.w;
    }
  }
  __syncthreads();
  // ---- transposed read -> Kt[s][c], coalesced 16B stores ----
  {
    bf16x8 o0, o1;
#pragma unroll
    for (int k = 0; k < 8; ++k) o0[k] = f2bf(lds[(part * 16 + k) * 65 + row]);
#pragma unroll
    for (int k = 0; k < 8; ++k) o1[k] = f2bf(lds[(part * 16 + 8 + k) * 65 + row]);
    short* dst = Kt + ((size_t)bh * 2048 + s0 + row) * 64 + part * 16;
    *(bf16x8*)dst = o0;
    *(bf16x8*)(dst + 8) = o1;
  }
  // ---- V: straight convert, both sides coalesced ----
  {
    const float* src = qkv + qb + (size_t)(128 + row) * 2048 + s0 + part * 16;
    float a[16];
#pragma unroll
    for (int k4 = 0; k4 < 4; ++k4) {
      float4 v = ((const float4*)src)[k4];
      a[k4 * 4 + 0] = v.x; a[k4 * 4 + 1] = v.y;
      a[k4 * 4 + 2] = v.z; a[k4 * 4 + 3] = v.w;
    }
    bf16x8 o0, o1;
#pragma unroll
    for (int k = 0; k < 8; ++k) { o0[k] = f2bf(a[k]); o1[k] = f2bf(a[8 + k]); }
    short* dst = Vb + ((size_t)bh * 64 + row) * 2048 + s0 + part * 16;
    *(bf16x8*)dst = o0;
    *(bf16x8*)(dst + 8) = o1;
  }
}

// ---------------------------------------------------------------------------
// Flash attention, 32x32x16 MFMA, in-register P (no LDS P-bounce).
// 1024 blocks (XCD-swizzled), 4 waves, wave owns 32 t. s-chunks of 64.
// Sync structure = round-4 verified: ds_write ch -> __syncthreads -> prefetch
// ch+1 (flies under compute) -> compute ch; K/V LDS double-buffered (32 KB).
//
// QK^T swapped: D = K*Q -> col = t = lane&31, row = s' = (r&3)+8*(r>>2)+4*hi
// (m74/m101-verified 32x32 C/D layout). Softmax fully per-lane (one t per
// lane) + one shfl_xor(32).
// P redistribution to PV A/B-fragment layout (k = hi*8+j contiguous), derived:
//   value s' = 16*kl + 8*hi_req + m is held by lane hi'=m>>2 at reg
//   8*kl + 4*hi_req + (m&3)  ->  per (st,kl): pack own reg pairs
//   p0{a,b} = regs 8kl..8kl+3 (serves hi_req=0), p1{a,b} = 8kl+4..+7
//   (serves hi_req=1); exchange with lane^32: send own-needed-by-partner
//   word, then select. 4 packs + 2 shfl + 6 sel per (st,kl).
// PV: acc[cb] = mfma(A=V(rows=c), B=pa(cols=t)) -> D col = t -> coalesced.
// ---------------------------------------------------------------------------
__global__ __launch_bounds__(256, 3) void attn32_kernel(
    const float* __restrict__ qkv, const short* __restrict__ Kt,
    const short* __restrict__ Vb, float* __restrict__ out) {
  const int bid = blockIdx.x;
  const int vid = (bid & 7) * 128 + (bid >> 3);  // bijective XCD swizzle
  const int bh = vid >> 4;
  const int tblk = vid & 15;
  const int tid = threadIdx.x;
  const int wv = tid >> 6;
  const int lane = tid & 63;
  const int tl = lane & 31;
  const int hi = lane >> 5;
  const int t0w = tblk * 128 + wv * 32;

  // [buf0: K 8K | V 8K][buf1: K 8K | V 8K]
  __shared__ __align__(16) char smem[32768];

  // ---- Q fragments (B-operand: col = t = lane&31, k = kc*16 + hi*8 + j) ----
  const size_t qb = (size_t)bh * (192 * 2048);
  bf16x8 qf[4];
#pragma unroll
  for (int kc = 0; kc < 4; ++kc) {
#pragma unroll
    for (int j = 0; j < 8; ++j) {
      const int c = kc * 16 + hi * 8 + j;
      qf[kc][j] = f2bf(qkv[qb + (size_t)c * 2048 + t0w + tl] * QSCALE);
    }
  }

  f32x16 acc[2];
#pragma unroll
  for (int cb = 0; cb < 2; ++cb)
#pragma unroll
    for (int r = 0; r < 16; ++r) acc[cb][r] = 0.f;

  float mrun = -1e30f;
  float lsum = 0.f;

  // staging geometry: 256 threads stage 64 rows of K and of V per chunk
  const int srow = tid >> 3;   // 0..31 (+32 on second q-step)
  const int col8 = tid & 7;    // 16B slot within 128B row
  const short* kptr = Kt + (size_t)bh * (2048 * 64) + (size_t)srow * 64 + col8 * 8;
  const short* vptr = Vb + ((size_t)bh * 64 + srow) * 2048 + col8 * 8;
  // (srow+32)&7 == srow&7 so the swizzle term is q-invariant
  const int sdst = srow * 128 + ((col8 * 16) ^ ((srow & 7) * 16));

  // ---- prologue: chunk 0 into regs ----
  bf16x8 kq[2], vq[2];
#pragma unroll
  for (int q = 0; q < 2; ++q) {
    kq[q] = *(const bf16x8*)(kptr + (size_t)(q * 32) * 64);
    vq[q] = *(const bf16x8*)(vptr + (size_t)(q * 32) * 2048);
  }

  for (int ch = 0; ch < 32; ++ch) {
    char* const Kls = smem + (ch & 1) * 16384;
    char* const Vls = Kls + 8192;

    // ---- write current chunk (regs prefetched one compute phase ago) ----
#pragma unroll
    for (int q = 0; q < 2; ++q) {
      *(bf16x8*)(Kls + sdst + q * 4096) = kq[q];
      *(bf16x8*)(Vls + sdst + q * 4096) = vq[q];
    }
    __syncthreads();

    // ---- issue next chunk's loads; they fly under this chunk's compute ----
    const int s0n = (ch < 31 ? ch + 1 : 31) * 64;
    bf16x8 kn[2], vn[2];
#pragma unroll
    for (int q = 0; q < 2; ++q) {
      kn[q] = *(const bf16x8*)(kptr + (size_t)(s0n + q * 32) * 64);
      vn[q] = *(const bf16x8*)(vptr + (size_t)(q * 32) * 2048 + s0n);
    }

    // ---- QK^T: two 32-s tiles, A = K (rows=s), B = Q (cols=t) ----
    f32x16 lg[2];
#pragma unroll
    for (int st = 0; st < 2; ++st) {
#pragma unroll
      for (int r = 0; r < 16; ++r) lg[st][r] = 0.f;
      const int row = st * 32 + tl;
      const int rsw = (row & 7) * 16;
#pragma unroll
      for (int kc = 0; kc < 4; ++kc) {
        const bf16x8 ka =
            *(const bf16x8*)(Kls + row * 128 + ((kc * 32 + hi * 16) ^ rsw));
        lg[st] = __builtin_amdgcn_mfma_f32_32x32x16_bf16(ka, qf[kc], lg[st],
                                                         0, 0, 0);
      }
    }

    // ---- online max over the 32 held logits + lane^32 exchange ----
    float cm = fmaxf(lg[0][0], lg[1][0]);
#pragma unroll
    for (int r = 1; r < 16; ++r) cm = fmaxf(cm, fmaxf(lg[0][r], lg[1][r]));
    cm = fmaxf(cm, __shfl_xor(cm, 32));
    if (!__all(cm <= mrun + 8.0f)) {   // deferred rescale, THR=8 (log2)
      const float nm = fmaxf(mrun, cm);
      const float fac = EXP2F(mrun - nm);
      mrun = nm;
      lsum *= fac;
#pragma unroll
      for (int cb = 0; cb < 2; ++cb)
#pragma unroll
        for (int r = 0; r < 16; ++r) acc[cb][r] *= fac;
    }

    // ---- P = exp2(lg - m), in place; per-lane partial sum ----
#pragma unroll
    for (int st = 0; st < 2; ++st)
#pragma unroll
      for (int r = 0; r < 16; ++r) {
        lg[st][r] = EXP2F(lg[st][r] - mrun);
        lsum += lg[st][r];
      }

    // ---- pack + redistribute P into PV fragments pa[ks] (k = hi*8+j) ----
    bf16x8 pa[4];
#pragma unroll
    for (int st = 0; st < 2; ++st) {
#pragma unroll
      for (int kl = 0; kl < 2; ++kl) {
        const unsigned int p0a = pkbf(lg[st][8 * kl + 0], lg[st][8 * kl + 1]);
        const unsigned int p0b = pkbf(lg[st][8 * kl + 2], lg[st][8 * kl + 3]);
        const unsigned int p1a = pkbf(lg[st][8 * kl + 4], lg[st][8 * kl + 5]);
        const unsigned int p1b = pkbf(lg[st][8 * kl + 6], lg[st][8 * kl + 7]);
        // partner (lane^32) needs: hi lane's p0* (serves lo's w2/w3),
        // lo lane's p1* (serves hi's w0/w1)
        const unsigned int sa = hi ? p0a : p1a;
        const unsigned int sb = hi ? p0b : p1b;
        const unsigned int ra = __shfl_xor(sa, 32);
        const unsigned int rb = __shfl_xor(sb, 32);
        union { unsigned int w[4]; bf16x8 v; } u;
        u.w[0] = hi ? ra : p0a;   // k-offsets 0,1
        u.w[1] = hi ? rb : p0b;   // 2,3
        u.w[2] = hi ? p1a : ra;   // 4,5
        u.w[3] = hi ? p1b : rb;   // 6,7
        pa[st * 2 + kl] = u.v;
      }
    }

    // ---- PV: acc[cb] += V * P  (A = V rows=c, B = pa cols=t) ----
#pragma unroll
    for (int cb = 0; cb < 2; ++cb) {
      const int rowv = cb * 32 + tl;
      const int vsw = (rowv & 7) * 16;
#pragma unroll
      for (int ks = 0; ks < 4; ++ks) {
        const bf16x8 vb =
            *(const bf16x8*)(Vls + rowv * 128 + ((ks * 32 + hi * 16) ^ vsw));
        acc[cb] = __builtin_amdgcn_mfma_f32_32x32x16_bf16(vb, pa[ks], acc[cb],
                                                          0, 0, 0);
      }
    }

    // ---- carry prefetched regs into next iteration ----
#pragma unroll
    for (int q = 0; q < 2; ++q) { kq[q] = kn[q]; vq[q] = vn[q]; }
  }

  // ---- epilogue: normalize + store (D: col=t=lane&31, row=c) ----
  const float ls = lsum + __shfl_xor(lsum, 32);
  const float inv = 1.0f / ls;
#pragma unroll
  for (int cb = 0; cb < 2; ++cb) {
#pragma unroll
    for (int r = 0; r < 16; ++r) {
      const int c = cb * 32 + (r & 3) + 8 * (r >> 2) + 4 * hi;
      out[((size_t)bh * 64 + c) * 2048 + t0w + tl] = acc[cb][r] * inv;
    }
  }
}

extern "C" void kernel_launch(void* const* d_in, const int* in_sizes, int n_in,
                              void* d_out, int out_size, void* d_ws,
                              size_t ws_size, hipStream_t stream) {
  (void)in_sizes; (void)n_in; (void)out_size;
  const float* qkv = (const float*)d_in[0];
  float* out = (float*)d_out;
  const size_t kv_elems = (size_t)64 * 2048 * 64;
  if (ws_size < kv_elems * 2 * sizeof(short)) return;  // need 32 MB scratch
  short* Kt = (short*)d_ws;
  short* Vb = Kt + kv_elems;
  hipLaunchKernelGGL(qkv_prep_kernel, dim3(2048), dim3(256), 0, stream,
                     qkv, Kt, Vb);
  hipLaunchKernelGGL(attn32_kernel, dim3(1024), dim3(256), 0, stream,
                     qkv, Kt, Vb, out);
}

// Round 6
// 125.516 us; speedup vs baseline: 1.0319x; 1.0319x over previous
//
#include <hip/hip_runtime.h>
#include <hip/hip_bf16.h>
#include <cstdint>
#include <cstddef>

typedef short bf16x8 __attribute__((ext_vector_type(8)));
typedef float f32x16 __attribute__((ext_vector_type(16)));

#if __has_builtin(__builtin_amdgcn_exp2f)
#define EXP2F(x) __builtin_amdgcn_exp2f(x)
#else
#define EXP2F(x) exp2f(x)
#endif

// scale^2 * log2(e) folded into Q; ch=64 -> (1/8)*1.4426950408889634
#define QSCALE 0.18033688011112043f

__device__ __forceinline__ short f2bf(float f) {
  union { __hip_bfloat16 b; short s; } u;
  u.b = __float2bfloat16(f);
  return u.s;
}

// RNE pack via scalar casts — compiler packs to v_cvt_pk (m240: beats asm)
__device__ __forceinline__ unsigned int packbf2(float a, float b) {
  union { unsigned short u[2]; unsigned int w; } x;
  x.u[0] = (unsigned short)f2bf(a);
  x.u[1] = (unsigned short)f2bf(b);
  return x.w;
}

// async global -> LDS, 16 B per lane; LDS dest = wave-uniform base + lane*16
__device__ __forceinline__ void gload16(const short* g, char* l) {
  __builtin_amdgcn_global_load_lds(
      (const __attribute__((address_space(1))) void*)g,
      (__attribute__((address_space(3))) void*)l, 16, 0, 0);
}

// ---------------------------------------------------------------------------
// Prepass: Kt[bh][s][c] = bf16(K[c][s]);  Vb[bh][c][s] = bf16(V[c][s]).
// qkv layout: [bh][cc][t], cc: 0..63 Q, 64..127 K, 128..191 V.
// ---------------------------------------------------------------------------
__global__ __launch_bounds__(256, 4) void qkv_prep_kernel(
    const float* __restrict__ qkv, short* __restrict__ Kt,
    short* __restrict__ Vb) {
  const int bh = blockIdx.x >> 5;
  const int s0 = (blockIdx.x & 31) << 6;
  const int tid = threadIdx.x;
  const int row = tid >> 2;   // 0..63
  const int part = tid & 3;   // 0..3  (16 columns each)
  __shared__ float lds[64 * 65];

  const size_t qb = (size_t)bh * (192 * 2048);

  // ---- K: load [c][s] tile coalesced into LDS ----
  {
    const float* src = qkv + qb + (size_t)(64 + row) * 2048 + s0 + part * 16;
#pragma unroll
    for (int k4 = 0; k4 < 4; ++k4) {
      float4 v = ((const float4*)src)[k4];
      float* p = &lds[row * 65 + part * 16 + k4 * 4];
      p[0] = v.x; p[1] = v.y; p[2] = v.z; p[3] = v.w;
    }
  }
  __syncthreads();
  // ---- transposed read -> Kt[s][c], coalesced 16B stores ----
  {
    bf16x8 o0, o1;
#pragma unroll
    for (int k = 0; k < 8; ++k) o0[k] = f2bf(lds[(part * 16 + k) * 65 + row]);
#pragma unroll
    for (int k = 0; k < 8; ++k) o1[k] = f2bf(lds[(part * 16 + 8 + k) * 65 + row]);
    short* dst = Kt + ((size_t)bh * 2048 + s0 + row) * 64 + part * 16;
    *(bf16x8*)dst = o0;
    *(bf16x8*)(dst + 8) = o1;
  }
  // ---- V: straight convert, both sides coalesced ----
  {
    const float* src = qkv + qb + (size_t)(128 + row) * 2048 + s0 + part * 16;
    float a[16];
#pragma unroll
    for (int k4 = 0; k4 < 4; ++k4) {
      float4 v = ((const float4*)src)[k4];
      a[k4 * 4 + 0] = v.x; a[k4 * 4 + 1] = v.y;
      a[k4 * 4 + 2] = v.z; a[k4 * 4 + 3] = v.w;
    }
    bf16x8 o0, o1;
#pragma unroll
    for (int k = 0; k < 8; ++k) { o0[k] = f2bf(a[k]); o1[k] = f2bf(a[8 + k]); }
    short* dst = Vb + ((size_t)bh * 64 + row) * 2048 + s0 + part * 16;
    *(bf16x8*)dst = o0;
    *(bf16x8*)(dst + 8) = o1;
  }
}

// ---------------------------------------------------------------------------
// Flash attention, 32x32x16 MFMA, in-register P, async gload_lds staging.
// 1024 blocks (XCD-swizzled), 4 waves, wave owns 32 t. s-chunks of 64.
// Staging (G21-correct): LDS dest LINEAR (wave base + lane*16); global
// source pre-swizzled (slot ^= row&7, involution), so LDS[row][s] holds
// G[row][s ^ (row&7)] — identical contents to the verified R5 reg-staged
// layout; compute-side swizzled reads unchanged.
// Loop: __syncthreads (its vmcnt(0) drains this chunk's prefetch) ->
//       issue gload_lds for ch+1 into buf^1 (flies under compute) ->
//       compute ch from buf.  One barrier per chunk, dbuf hazard-free.
// QK^T swapped (A=K rows=s, B=Q cols=t); per-lane softmax + shfl_xor(32);
// P packed+redistributed in-register to the PV B-fragment (R5-verified);
// PV A=V(rows=c) -> D col=t -> coalesced stores.
// ---------------------------------------------------------------------------
__global__ __launch_bounds__(256, 4) void attn32_kernel(
    const float* __restrict__ qkv, const short* __restrict__ Kt,
    const short* __restrict__ Vb, float* __restrict__ out) {
  const int bid = blockIdx.x;
  const int vid = (bid & 7) * 128 + (bid >> 3);  // bijective XCD swizzle
  const int bh = vid >> 4;
  const int tblk = vid & 15;
  const int tid = threadIdx.x;
  const int wv = tid >> 6;
  const int lane = tid & 63;
  const int tl = lane & 31;
  const int hi = lane >> 5;
  const int t0w = tblk * 128 + wv * 32;

  // [buf0: K 8K | V 8K][buf1: K 8K | V 8K]
  __shared__ __align__(16) char smem[32768];

  // ---- Q fragments (B-operand: col = t = lane&31, k = kc*16 + hi*8 + j) ----
  const size_t qb = (size_t)bh * (192 * 2048);
  bf16x8 qf[4];
#pragma unroll
  for (int kc = 0; kc < 4; ++kc) {
#pragma unroll
    for (int j = 0; j < 8; ++j) {
      const int c = kc * 16 + hi * 8 + j;
      qf[kc][j] = f2bf(qkv[qb + (size_t)c * 2048 + t0w + tl] * QSCALE);
    }
  }

  f32x16 acc[2];
#pragma unroll
  for (int cb = 0; cb < 2; ++cb)
#pragma unroll
    for (int r = 0; r < 16; ++r) acc[cb][r] = 0.f;

  float mrun = -1e30f;
  float lsum = 0.f;

  // ---- staging geometry (async): wave wv stages rows [wv*16, wv*16+16)
  // of K (s-rows) and of V (c-rows); 2 gload_lds each, 8 rows per gload.
  const int r8 = lane >> 3;   // row within 8-row group
  const int sl = lane & 7;    // 16B slot
  const int row0 = wv * 16 + r8;       // q=0 row
  const int row1 = wv * 16 + 8 + r8;   // q=1 row
  // pre-swizzled global sources (slot ^ (row&7)); involution matches reads
  const short* kg0 = Kt + (size_t)bh * (2048 * 64) + (size_t)row0 * 64 +
                     ((sl ^ (row0 & 7)) * 8);
  const short* kg1 = Kt + (size_t)bh * (2048 * 64) + (size_t)row1 * 64 +
                     ((sl ^ (row1 & 7)) * 8);
  const short* vg0 = Vb + ((size_t)bh * 64 + row0) * 2048 +
                     ((sl ^ (row0 & 7)) * 8);
  const short* vg1 = Vb + ((size_t)bh * 64 + row1) * 2048 +
                     ((sl ^ (row1 & 7)) * 8);
  // wave-uniform LDS byte offsets (lane*16 added by HW)
  const int ldK0 = (wv * 16) * 128;
  const int ldK1 = (wv * 16 + 8) * 128;

  // ---- prologue: stage chunk 0 into buf0 ----
  {
    gload16(kg0, smem + ldK0);
    gload16(kg1, smem + ldK1);
    gload16(vg0, smem + 8192 + ldK0);
    gload16(vg1, smem + 8192 + ldK1);
  }

#pragma unroll 2
  for (int ch = 0; ch < 32; ++ch) {
    char* const Kls = smem + (ch & 1) * 16384;
    char* const Vls = Kls + 8192;

    // barrier: (a) all waves done reading buf^1, (b) vmcnt(0) inside the
    // barrier drains this chunk's prefetch -> buf ready
    __syncthreads();

    // ---- issue next chunk's staging; flies under this chunk's compute ----
    if (ch < 31) {
      char* const Knx = smem + ((ch + 1) & 1) * 16384;
      const size_t ka = (size_t)(ch + 1) * 4096;   // 64 rows * 64 ch
      const int va = (ch + 1) * 64;                // 64 s along the row
      gload16(kg0 + ka, Knx + ldK0);
      gload16(kg1 + ka, Knx + ldK1);
      gload16(vg0 + va, Knx + 8192 + ldK0);
      gload16(vg1 + va, Knx + 8192 + ldK1);
    }

    // ---- QK^T: two 32-s tiles, A = K (rows=s), B = Q (cols=t) ----
    f32x16 lg[2];
#pragma unroll
    for (int st = 0; st < 2; ++st) {
#pragma unroll
      for (int r = 0; r < 16; ++r) lg[st][r] = 0.f;
      const int row = st * 32 + tl;
      const int rsw = (row & 7) * 16;
#pragma unroll
      for (int kc = 0; kc < 4; ++kc) {
        const bf16x8 ka =
            *(const bf16x8*)(Kls + row * 128 + ((kc * 32 + hi * 16) ^ rsw));
        lg[st] = __builtin_amdgcn_mfma_f32_32x32x16_bf16(ka, qf[kc], lg[st],
                                                         0, 0, 0);
      }
    }

    // ---- online max (depth-5 tree) + lane^32 exchange ----
    float mt[16];
#pragma unroll
    for (int r = 0; r < 16; ++r) mt[r] = fmaxf(lg[0][r], lg[1][r]);
#pragma unroll
    for (int s = 8; s >= 1; s >>= 1)
#pragma unroll
      for (int r = 0; r < 8; ++r)
        if (r < s) mt[r] = fmaxf(mt[r], mt[r + s]);
    float cm = fmaxf(mt[0], __shfl_xor(mt[0], 32));
    if (!__all(cm <= mrun + 8.0f)) {   // deferred rescale, THR=8 (log2)
      const float nm = fmaxf(mrun, cm);
      const float fac = EXP2F(mrun - nm);
      mrun = nm;
      lsum *= fac;
#pragma unroll
      for (int cb = 0; cb < 2; ++cb)
#pragma unroll
        for (int r = 0; r < 16; ++r) acc[cb][r] *= fac;
    }

    // ---- P = exp2(lg - m) in place; pairwise partial sum ----
    float ps = 0.f;
#pragma unroll
    for (int st = 0; st < 2; ++st) {
#pragma unroll
      for (int r = 0; r < 16; ++r) lg[st][r] = EXP2F(lg[st][r] - mrun);
#pragma unroll
      for (int r = 0; r < 8; ++r) ps += lg[st][2 * r] + lg[st][2 * r + 1];
    }
    lsum += ps;

    // ---- pack + redistribute P into PV fragments pa[ks] (k = hi*8+j) ----
    bf16x8 pa[4];
#pragma unroll
    for (int st = 0; st < 2; ++st) {
#pragma unroll
      for (int kl = 0; kl < 2; ++kl) {
        const unsigned int p0a = packbf2(lg[st][8 * kl + 0], lg[st][8 * kl + 1]);
        const unsigned int p0b = packbf2(lg[st][8 * kl + 2], lg[st][8 * kl + 3]);
        const unsigned int p1a = packbf2(lg[st][8 * kl + 4], lg[st][8 * kl + 5]);
        const unsigned int p1b = packbf2(lg[st][8 * kl + 6], lg[st][8 * kl + 7]);
        const unsigned int sa = hi ? p0a : p1a;
        const unsigned int sb = hi ? p0b : p1b;
        const unsigned int ra = __shfl_xor(sa, 32);
        const unsigned int rb = __shfl_xor(sb, 32);
        union { unsigned int w[4]; bf16x8 v; } u;
        u.w[0] = hi ? ra : p0a;   // k-offsets 0,1
        u.w[1] = hi ? rb : p0b;   // 2,3
        u.w[2] = hi ? p1a : ra;   // 4,5
        u.w[3] = hi ? p1b : rb;   // 6,7
        pa[st * 2 + kl] = u.v;
      }
    }

    // ---- PV: acc[cb] += V * P  (A = V rows=c, B = pa cols=t) ----
#pragma unroll
    for (int cb = 0; cb < 2; ++cb) {
      const int rowv = cb * 32 + tl;
      const int vsw = (rowv & 7) * 16;
#pragma unroll
      for (int ks = 0; ks < 4; ++ks) {
        const bf16x8 vb =
            *(const bf16x8*)(Vls + rowv * 128 + ((ks * 32 + hi * 16) ^ vsw));
        acc[cb] = __builtin_amdgcn_mfma_f32_32x32x16_bf16(vb, pa[ks], acc[cb],
                                                          0, 0, 0);
      }
    }
  }

  // ---- epilogue: normalize + store (D: col=t=lane&31, row=c) ----
  const float ls = lsum + __shfl_xor(lsum, 32);
  const float inv = 1.0f / ls;
#pragma unroll
  for (int cb = 0; cb < 2; ++cb) {
#pragma unroll
    for (int r = 0; r < 16; ++r) {
      const int c = cb * 32 + (r & 3) + 8 * (r >> 2) + 4 * hi;
      out[((size_t)bh * 64 + c) * 2048 + t0w + tl] = acc[cb][r] * inv;
    }
  }
}

extern "C" void kernel_launch(void* const* d_in, const int* in_sizes, int n_in,
                              void* d_out, int out_size, void* d_ws,
                              size_t ws_size, hipStream_t stream) {
  (void)in_sizes; (void)n_in; (void)out_size;
  const float* qkv = (const float*)d_in[0];
  float* out = (float*)d_out;
  const size_t kv_elems = (size_t)64 * 2048 * 64;
  if (ws_size < kv_elems * 2 * sizeof(short)) return;  // need 32 MB scratch
  short* Kt = (short*)d_ws;
  short* Vb = Kt + kv_elems;
  hipLaunchKernelGGL(qkv_prep_kernel, dim3(2048), dim3(256), 0, stream,
                     qkv, Kt, Vb);
  hipLaunchKernelGGL(attn32_kernel, dim3(1024), dim3(256), 0, stream,
                     qkv, Kt, Vb, out);
}

// Round 9
// 122.627 us; speedup vs baseline: 1.0562x; 1.0236x over previous
//
#include <hip/hip_runtime.h>
#include <hip/hip_bf16.h>
#include <cstdint>
#include <cstddef>

typedef short bf16x8 __attribute__((ext_vector_type(8)));
typedef float f32x16 __attribute__((ext_vector_type(16)));
typedef unsigned int uint2v __attribute__((ext_vector_type(2)));

#if __has_builtin(__builtin_amdgcn_exp2f)
#define EXP2F(x) __builtin_amdgcn_exp2f(x)
#else
#define EXP2F(x) exp2f(x)
#endif

// scale^2 * log2(e) folded into Q; ch=64 -> (1/8)*1.4426950408889634
#define QSCALE 0.18033688011112043f

__device__ __forceinline__ short f2bf(float f) {
  union { __hip_bfloat16 b; short s; } u;
  u.b = __float2bfloat16(f);
  return u.s;
}

__device__ __forceinline__ unsigned int fbits(float f) {
  union { float f; unsigned int u; } x; x.f = f; return x.u;
}
__device__ __forceinline__ float bfloat(unsigned int u) {
  union { unsigned int u; float f; } x; x.u = u; return x.f;
}

// fast packed f32x2 -> bf16x2, round-half-up (R5-verified: softmax P values
// are finite positives; bias vs RNE <= 1 ulp on exact halves, prob 2^-16)
__device__ __forceinline__ unsigned int pkbf(float a, float b) {
  return ((fbits(a) + 0x8000u) >> 16) | ((fbits(b) + 0x8000u) & 0xFFFF0000u);
}

// permlane32_swap builtin — used ONLY for commutative own+partner combines,
// which are correct under ANY half-swap convention (results always contain
// {own, partner} as a set per lane).
__device__ __forceinline__ float fmax_x32(float v) {
  const uint2v r = __builtin_amdgcn_permlane32_swap(fbits(v), fbits(v),
                                                    false, false);
  return fmaxf(bfloat(r[0]), bfloat(r[1]));
}
__device__ __forceinline__ float fadd_x32(float v) {
  const uint2v r = __builtin_amdgcn_permlane32_swap(fbits(v), fbits(v),
                                                    false, false);
  return bfloat(r[0]) + bfloat(r[1]);
}

// async global -> LDS, 16 B per lane; LDS dest = wave-uniform base + lane*16
__device__ __forceinline__ void gload16(const short* g, char* l) {
  __builtin_amdgcn_global_load_lds(
      (const __attribute__((address_space(1))) void*)g,
      (__attribute__((address_space(3))) void*)l, 16, 0, 0);
}

// ---------------------------------------------------------------------------
// Prepass: Kt[bh][s][c] = bf16(K[c][s]);  Vb[bh][c][s] = bf16(V[c][s]).
// qkv layout: [bh][cc][t], cc: 0..63 Q, 64..127 K, 128..191 V.
// ---------------------------------------------------------------------------
__global__ __launch_bounds__(256, 4) void qkv_prep_kernel(
    const float* __restrict__ qkv, short* __restrict__ Kt,
    short* __restrict__ Vb) {
  const int bh = blockIdx.x >> 5;
  const int s0 = (blockIdx.x & 31) << 6;
  const int tid = threadIdx.x;
  const int row = tid >> 2;   // 0..63
  const int part = tid & 3;   // 0..3  (16 columns each)
  __shared__ float lds[64 * 65];

  const size_t qb = (size_t)bh * (192 * 2048);

  // ---- K: load [c][s] tile coalesced into LDS ----
  {
    const float* src = qkv + qb + (size_t)(64 + row) * 2048 + s0 + part * 16;
#pragma unroll
    for (int k4 = 0; k4 < 4; ++k4) {
      float4 v = ((const float4*)src)[k4];
      float* p = &lds[row * 65 + part * 16 + k4 * 4];
      p[0] = v.x; p[1] = v.y; p[2] = v.z; p[3] = v.w;
    }
  }
  __syncthreads();
  // ---- transposed read -> Kt[s][c], coalesced 16B stores ----
  {
    bf16x8 o0, o1;
#pragma unroll
    for (int k = 0; k < 8; ++k) o0[k] = f2bf(lds[(part * 16 + k) * 65 + row]);
#pragma unroll
    for (int k = 0; k < 8; ++k) o1[k] = f2bf(lds[(part * 16 + 8 + k) * 65 + row]);
    short* dst = Kt + ((size_t)bh * 2048 + s0 + row) * 64 + part * 16;
    *(bf16x8*)dst = o0;
    *(bf16x8*)(dst + 8) = o1;
  }
  // ---- V: straight convert, both sides coalesced ----
  {
    const float* src = qkv + qb + (size_t)(128 + row) * 2048 + s0 + part * 16;
    float a[16];
#pragma unroll
    for (int k4 = 0; k4 < 4; ++k4) {
      float4 v = ((const float4*)src)[k4];
      a[k4 * 4 + 0] = v.x; a[k4 * 4 + 1] = v.y;
      a[k4 * 4 + 2] = v.z; a[k4 * 4 + 3] = v.w;
    }
    bf16x8 o0, o1;
#pragma unroll
    for (int k = 0; k < 8; ++k) { o0[k] = f2bf(a[k]); o1[k] = f2bf(a[8 + k]); }
    short* dst = Vb + ((size_t)bh * 64 + row) * 2048 + s0 + part * 16;
    *(bf16x8*)dst = o0;
    *(bf16x8*)(dst + 8) = o1;
  }
}

// ---------------------------------------------------------------------------
// Flash attention, 32x32x16 MFMA, in-register P, async gload_lds staging.
// All pieces individually verified: staging/sync = R6; redistribution +
// pkbf pack = R5; permlane reductions = convention-independent; max3 tree
// + hoisted offsets = reviewed (R8's sole bug was the plswap redistribution).
// ---------------------------------------------------------------------------
__global__ __launch_bounds__(256, 4) void attn32_kernel(
    const float* __restrict__ qkv, const short* __restrict__ Kt,
    const short* __restrict__ Vb, float* __restrict__ out) {
  const int bid = blockIdx.x;
  const int vid = (bid & 7) * 128 + (bid >> 3);  // bijective XCD swizzle
  const int bh = vid >> 4;
  const int tblk = vid & 15;
  const int tid = threadIdx.x;
  const int wv = tid >> 6;
  const int lane = tid & 63;
  const int tl = lane & 31;
  const int hi = lane >> 5;
  const int t0w = tblk * 128 + wv * 32;

  // [buf0: K 8K | V 8K][buf1: K 8K | V 8K]
  __shared__ __align__(16) char smem[32768];

  // ---- Q fragments (B-operand: col = t = lane&31, k = kc*16 + hi*8 + j) ----
  const size_t qb = (size_t)bh * (192 * 2048);
  bf16x8 qf[4];
#pragma unroll
  for (int kc = 0; kc < 4; ++kc) {
#pragma unroll
    for (int j = 0; j < 8; ++j) {
      const int c = kc * 16 + hi * 8 + j;
      qf[kc][j] = f2bf(qkv[qb + (size_t)c * 2048 + t0w + tl] * QSCALE);
    }
  }

  // persistent zero C-operand (avoids 32 per-chunk zero-init movs)
  f32x16 zv;
#pragma unroll
  for (int r = 0; r < 16; ++r) zv[r] = 0.f;

  f32x16 acc[2];
#pragma unroll
  for (int cb = 0; cb < 2; ++cb) acc[cb] = zv;

  float mrun = -1e30f;
  float lsum = 0.f;

  // ---- hoisted LDS read offsets: one table serves QK (rows=s) and PV
  // (rows=c): off[x][j] = (x*32+tl)*128 + ((j*32+hi*16) ^ rsw) ----
  const int rsw = (tl & 7) * 16;
  int off[2][4];
#pragma unroll
  for (int x = 0; x < 2; ++x)
#pragma unroll
    for (int j = 0; j < 4; ++j)
      off[x][j] = (x * 32 + tl) * 128 + ((j * 32 + hi * 16) ^ rsw);

  // ---- staging geometry (async): wave wv stages rows [wv*16, wv*16+16) ----
  const int r8 = lane >> 3;   // row within 8-row group
  const int sl = lane & 7;    // 16B slot
  const int row0 = wv * 16 + r8;       // first 8-row group
  const int row1 = wv * 16 + 8 + r8;   // second
  // pre-swizzled global sources (slot ^ (row&7)); involution matches reads
  const short* kg0 = Kt + (size_t)bh * (2048 * 64) + (size_t)row0 * 64 +
                     ((sl ^ (row0 & 7)) * 8);
  const short* kg1 = Kt + (size_t)bh * (2048 * 64) + (size_t)row1 * 64 +
                     ((sl ^ (row1 & 7)) * 8);
  const short* vg0 = Vb + ((size_t)bh * 64 + row0) * 2048 +
                     ((sl ^ (row0 & 7)) * 8);
  const short* vg1 = Vb + ((size_t)bh * 64 + row1) * 2048 +
                     ((sl ^ (row1 & 7)) * 8);
  // wave-uniform LDS byte offsets (lane*16 added by HW)
  const int ldK0 = (wv * 16) * 128;
  const int ldK1 = (wv * 16 + 8) * 128;

  // ---- prologue: stage chunk 0 into buf0 ----
  {
    gload16(kg0, smem + ldK0);
    gload16(kg1, smem + ldK1);
    gload16(vg0, smem + 8192 + ldK0);
    gload16(vg1, smem + 8192 + ldK1);
  }

#pragma unroll 2
  for (int ch = 0; ch < 32; ++ch) {
    char* const Kls = smem + (ch & 1) * 16384;
    char* const Vls = Kls + 8192;

    // barrier: (a) all waves done reading buf^1, (b) vmcnt(0) inside the
    // barrier drains this chunk's prefetch -> buf ready
    __syncthreads();

    // ---- issue next chunk's staging; flies under this chunk's compute ----
    if (ch < 31) {
      char* const Knx = smem + ((ch + 1) & 1) * 16384;
      const size_t ka = (size_t)(ch + 1) * 4096;   // 64 rows * 64 ch
      const int va = (ch + 1) * 64;                // 64 s along the row
      gload16(kg0 + ka, Knx + ldK0);
      gload16(kg1 + ka, Knx + ldK1);
      gload16(vg0 + va, Knx + 8192 + ldK0);
      gload16(vg1 + va, Knx + 8192 + ldK1);
    }

    // ---- QK^T: two 32-s tiles, A = K (rows=s), B = Q (cols=t) ----
    f32x16 lg[2];
#pragma unroll
    for (int st = 0; st < 2; ++st) {
      bf16x8 ka = *(const bf16x8*)(Kls + off[st][0]);
      lg[st] = __builtin_amdgcn_mfma_f32_32x32x16_bf16(ka, qf[0], zv, 0, 0, 0);
#pragma unroll
      for (int kc = 1; kc < 4; ++kc) {
        ka = *(const bf16x8*)(Kls + off[st][kc]);
        lg[st] = __builtin_amdgcn_mfma_f32_32x32x16_bf16(ka, qf[kc], lg[st],
                                                         0, 0, 0);
      }
    }

    // ---- online max: max3-shaped tree + permlane cross-half ----
    float w[11];
#pragma unroll
    for (int i = 0; i < 5; ++i)
      w[i] = fmaxf(fmaxf(lg[0][3 * i], lg[0][3 * i + 1]), lg[0][3 * i + 2]);
    w[5] = fmaxf(fmaxf(lg[0][15], lg[1][0]), lg[1][1]);
#pragma unroll
    for (int i = 0; i < 4; ++i)
      w[6 + i] = fmaxf(fmaxf(lg[1][3 * i + 2], lg[1][3 * i + 3]),
                       lg[1][3 * i + 4]);
    w[10] = fmaxf(lg[1][14], lg[1][15]);
    const float x0 = fmaxf(fmaxf(w[0], w[1]), w[2]);
    const float x1 = fmaxf(fmaxf(w[3], w[4]), w[5]);
    const float x2 = fmaxf(fmaxf(w[6], w[7]), w[8]);
    const float x3 = fmaxf(w[9], w[10]);
    float cm = fmax_x32(fmaxf(fmaxf(x0, x1), fmaxf(x2, x3)));
    if (!__all(cm <= mrun + 8.0f)) {   // deferred rescale, THR=8 (log2)
      const float nm = fmaxf(mrun, cm);
      const float fac = EXP2F(mrun - nm);
      mrun = nm;
      lsum *= fac;
#pragma unroll
      for (int cb = 0; cb < 2; ++cb)
#pragma unroll
        for (int r = 0; r < 16; ++r) acc[cb][r] *= fac;
    }

    // ---- P = exp2(lg - m) in place; pairwise partial sum ----
    float ps = 0.f;
#pragma unroll
    for (int st = 0; st < 2; ++st) {
#pragma unroll
      for (int r = 0; r < 16; ++r) lg[st][r] = EXP2F(lg[st][r] - mrun);
#pragma unroll
      for (int r = 0; r < 8; ++r) ps += lg[st][2 * r] + lg[st][2 * r + 1];
    }
    lsum += ps;

    // ---- pack + redistribute P -> PV fragments pa[ks] (R5-verified) ----
    // hi=0 lane needs: w0=own p0a, w1=own p0b, w2=partner p0a, w3=partner p0b
    // hi=1 lane needs: w0=partner p1a, w1=partner p1b, w2=own p1a, w3=own p1b
    bf16x8 pa[4];
#pragma unroll
    for (int st = 0; st < 2; ++st) {
#pragma unroll
      for (int kl = 0; kl < 2; ++kl) {
        const unsigned int p0a = pkbf(lg[st][8 * kl + 0], lg[st][8 * kl + 1]);
        const unsigned int p0b = pkbf(lg[st][8 * kl + 2], lg[st][8 * kl + 3]);
        const unsigned int p1a = pkbf(lg[st][8 * kl + 4], lg[st][8 * kl + 5]);
        const unsigned int p1b = pkbf(lg[st][8 * kl + 6], lg[st][8 * kl + 7]);
        const unsigned int sa = hi ? p0a : p1a;
        const unsigned int sb = hi ? p0b : p1b;
        const unsigned int ra = __shfl_xor(sa, 32);
        const unsigned int rb = __shfl_xor(sb, 32);
        union { unsigned int w[4]; bf16x8 v; } u;
        u.w[0] = hi ? ra : p0a;   // k-offsets 0,1
        u.w[1] = hi ? rb : p0b;   // 2,3
        u.w[2] = hi ? p1a : ra;   // 4,5
        u.w[3] = hi ? p1b : rb;   // 6,7
        pa[st * 2 + kl] = u.v;
      }
    }

    // ---- PV: acc[cb] += V * P  (A = V rows=c, B = pa cols=t) ----
#pragma unroll
    for (int cb = 0; cb < 2; ++cb) {
#pragma unroll
      for (int ks = 0; ks < 4; ++ks) {
        const bf16x8 vb = *(const bf16x8*)(Vls + off[cb][ks]);
        acc[cb] = __builtin_amdgcn_mfma_f32_32x32x16_bf16(vb, pa[ks], acc[cb],
                                                          0, 0, 0);
      }
    }
  }

  // ---- epilogue: normalize + store (D: col=t=lane&31, row=c) ----
  const float ls = fadd_x32(lsum);
  const float inv = 1.0f / ls;
#pragma unroll
  for (int cb = 0; cb < 2; ++cb) {
#pragma unroll
    for (int r = 0; r < 16; ++r) {
      const int c = cb * 32 + (r & 3) + 8 * (r >> 2) + 4 * hi;
      out[((size_t)bh * 64 + c) * 2048 + t0w + tl] = acc[cb][r] * inv;
    }
  }
}

extern "C" void kernel_launch(void* const* d_in, const int* in_sizes, int n_in,
                              void* d_out, int out_size, void* d_ws,
                              size_t ws_size, hipStream_t stream) {
  (void)in_sizes; (void)n_in; (void)out_size;
  const float* qkv = (const float*)d_in[0];
  float* out = (float*)d_out;
  const size_t kv_elems = (size_t)64 * 2048 * 64;
  if (ws_size < kv_elems * 2 * sizeof(short)) return;  // need 32 MB scratch
  short* Kt = (short*)d_ws;
  short* Vb = Kt + kv_elems;
  hipLaunchKernelGGL(qkv_prep_kernel, dim3(2048), dim3(256), 0, stream,
                     qkv, Kt, Vb);
  hipLaunchKernelGGL(attn32_kernel, dim3(1024), dim3(256), 0, stream,
                     qkv, Kt, Vb, out);
}

// Round 10
// 116.862 us; speedup vs baseline: 1.1083x; 1.0493x over previous
//
#include <hip/hip_runtime.h>
#include <hip/hip_bf16.h>
#include <cstdint>
#include <cstddef>

typedef short bf16x8 __attribute__((ext_vector_type(8)));
typedef float f32x16 __attribute__((ext_vector_type(16)));
typedef unsigned int uint2v __attribute__((ext_vector_type(2)));

#if __has_builtin(__builtin_amdgcn_exp2f)
#define EXP2F(x) __builtin_amdgcn_exp2f(x)
#else
#define EXP2F(x) exp2f(x)
#endif

// scale^2 * log2(e) folded into Q; ch=64 -> (1/8)*1.4426950408889634
#define QSCALE 0.18033688011112043f

__device__ __forceinline__ short f2bf(float f) {
  union { __hip_bfloat16 b; short s; } u;
  u.b = __float2bfloat16(f);
  return u.s;
}

__device__ __forceinline__ unsigned int fbits(float f) {
  union { float f; unsigned int u; } x; x.f = f; return x.u;
}
__device__ __forceinline__ float bfloat(unsigned int u) {
  union { unsigned int u; float f; } x; x.u = u; return x.f;
}

// fast packed f32x2 -> bf16x2, round-half-up (R5-verified on softmax P)
__device__ __forceinline__ unsigned int pkbf(float a, float b) {
  return ((fbits(a) + 0x8000u) >> 16) | ((fbits(b) + 0x8000u) & 0xFFFF0000u);
}

// permlane32_swap builtin — ONLY for commutative own+partner combines
// (correct under any half-swap convention; results contain {own,partner})
__device__ __forceinline__ float fmax_x32(float v) {
  const uint2v r = __builtin_amdgcn_permlane32_swap(fbits(v), fbits(v),
                                                    false, false);
  return fmaxf(bfloat(r[0]), bfloat(r[1]));
}
__device__ __forceinline__ float fadd_x32(float v) {
  const uint2v r = __builtin_amdgcn_permlane32_swap(fbits(v), fbits(v),
                                                    false, false);
  return bfloat(r[0]) + bfloat(r[1]);
}

// async global -> LDS, 16 B per lane; LDS dest = wave-uniform base + lane*16
__device__ __forceinline__ void gload16(const short* g, char* l) {
  __builtin_amdgcn_global_load_lds(
      (const __attribute__((address_space(1))) void*)g,
      (__attribute__((address_space(3))) void*)l, 16, 0, 0);
}

// ---------------------------------------------------------------------------
// Prepass: Kt[bh][s][c] = bf16(K[c][s]);  Vb[bh][c][s] = bf16(V[c][s]).
// qkv layout: [bh][cc][t], cc: 0..63 Q, 64..127 K, 128..191 V.
// ---------------------------------------------------------------------------
__global__ __launch_bounds__(256, 4) void qkv_prep_kernel(
    const float* __restrict__ qkv, short* __restrict__ Kt,
    short* __restrict__ Vb) {
  const int bh = blockIdx.x >> 5;
  const int s0 = (blockIdx.x & 31) << 6;
  const int tid = threadIdx.x;
  const int row = tid >> 2;   // 0..63
  const int part = tid & 3;   // 0..3  (16 columns each)
  __shared__ float lds[64 * 65];

  const size_t qb = (size_t)bh * (192 * 2048);

  // ---- K: load [c][s] tile coalesced into LDS ----
  {
    const float* src = qkv + qb + (size_t)(64 + row) * 2048 + s0 + part * 16;
#pragma unroll
    for (int k4 = 0; k4 < 4; ++k4) {
      float4 v = ((const float4*)src)[k4];
      float* p = &lds[row * 65 + part * 16 + k4 * 4];
      p[0] = v.x; p[1] = v.y; p[2] = v.z; p[3] = v.w;
    }
  }
  __syncthreads();
  // ---- transposed read -> Kt[s][c], coalesced 16B stores ----
  {
    bf16x8 o0, o1;
#pragma unroll
    for (int k = 0; k < 8; ++k) o0[k] = f2bf(lds[(part * 16 + k) * 65 + row]);
#pragma unroll
    for (int k = 0; k < 8; ++k) o1[k] = f2bf(lds[(part * 16 + 8 + k) * 65 + row]);
    short* dst = Kt + ((size_t)bh * 2048 + s0 + row) * 64 + part * 16;
    *(bf16x8*)dst = o0;
    *(bf16x8*)(dst + 8) = o1;
  }
  // ---- V: straight convert, both sides coalesced ----
  {
    const float* src = qkv + qb + (size_t)(128 + row) * 2048 + s0 + part * 16;
    float a[16];
#pragma unroll
    for (int k4 = 0; k4 < 4; ++k4) {
      float4 v = ((const float4*)src)[k4];
      a[k4 * 4 + 0] = v.x; a[k4 * 4 + 1] = v.y;
      a[k4 * 4 + 2] = v.z; a[k4 * 4 + 3] = v.w;
    }
    bf16x8 o0, o1;
#pragma unroll
    for (int k = 0; k < 8; ++k) { o0[k] = f2bf(a[k]); o1[k] = f2bf(a[8 + k]); }
    short* dst = Vb + ((size_t)bh * 64 + row) * 2048 + s0 + part * 16;
    *(bf16x8*)dst = o0;
    *(bf16x8*)(dst + 8) = o1;
  }
}

// ---------------------------------------------------------------------------
// Flash attention, 8-wave blocks for occupancy. 512 blocks (XCD-swizzled:
// 64 bh x 8 t-tiles of 256), 512 threads = 8 waves, wave owns 32 t.
// 2 blocks/CU -> 16 waves/CU; 4 waves/SIMD from 2 phase-uncorrelated blocks.
// K/V LDS (32 KB dbuf) shared by all 8 waves; staging = 1 K + 1 V
// gload_lds per wave per chunk (512 threads cover the 64x128B tile).
// Compute structure identical to R9 (verified): R6 sync, R5 fragments,
// permlane reductions, max3 tree, hoisted offsets, pkbf pack.
// ---------------------------------------------------------------------------
__global__ __launch_bounds__(512, 4) void attn32_kernel(
    const float* __restrict__ qkv, const short* __restrict__ Kt,
    const short* __restrict__ Vb, float* __restrict__ out) {
  const int bid = blockIdx.x;
  const int vid = (bid & 7) * 64 + (bid >> 3);  // bijective XCD swizzle (512)
  const int bh = vid >> 3;
  const int tblk = vid & 7;
  const int tid = threadIdx.x;
  const int wv = tid >> 6;          // 0..7
  const int lane = tid & 63;
  const int tl = lane & 31;
  const int hi = lane >> 5;
  const int t0w = tblk * 256 + wv * 32;

  // [buf0: K 8K | V 8K][buf1: K 8K | V 8K]
  __shared__ __align__(16) char smem[32768];

  // ---- Q fragments (B-operand: col = t = lane&31, k = kc*16 + hi*8 + j) ----
  const size_t qb = (size_t)bh * (192 * 2048);
  bf16x8 qf[4];
#pragma unroll
  for (int kc = 0; kc < 4; ++kc) {
#pragma unroll
    for (int j = 0; j < 8; ++j) {
      const int c = kc * 16 + hi * 8 + j;
      qf[kc][j] = f2bf(qkv[qb + (size_t)c * 2048 + t0w + tl] * QSCALE);
    }
  }

  // persistent zero C-operand (avoids per-chunk zero-init movs)
  f32x16 zv;
#pragma unroll
  for (int r = 0; r < 16; ++r) zv[r] = 0.f;

  f32x16 acc[2];
#pragma unroll
  for (int cb = 0; cb < 2; ++cb) acc[cb] = zv;

  float mrun = -1e30f;
  float lsum = 0.f;

  // ---- hoisted LDS read offsets: one table serves QK (rows=s) and PV
  // (rows=c): off[x][j] = (x*32+tl)*128 + ((j*32+hi*16) ^ rsw) ----
  const int rsw = (tl & 7) * 16;
  int off[2][4];
#pragma unroll
  for (int x = 0; x < 2; ++x)
#pragma unroll
    for (int j = 0; j < 4; ++j)
      off[x][j] = (x * 32 + tl) * 128 + ((j * 32 + hi * 16) ^ rsw);

  // ---- staging geometry: 512 threads cover all 64 rows in one pass ----
  const int srow = tid >> 3;   // 0..63
  const int sl = tid & 7;      // 16B slot within 128B row
  // pre-swizzled global sources (slot ^ (row&7)); involution matches reads
  const short* kg = Kt + (size_t)bh * (2048 * 64) + (size_t)srow * 64 +
                    ((sl ^ (srow & 7)) * 8);
  const short* vg = Vb + ((size_t)bh * 64 + srow) * 2048 +
                    ((sl ^ (srow & 7)) * 8);
  // wave-uniform LDS byte offset (lane*16 added by HW):
  // wave wv covers rows [wv*8, wv*8+8): base = wv*8*128 = wv*1024
  const int ldb = wv * 1024;

  // ---- prologue: stage chunk 0 into buf0 ----
  gload16(kg, smem + ldb);
  gload16(vg, smem + 8192 + ldb);

#pragma unroll 2
  for (int ch = 0; ch < 32; ++ch) {
    char* const Kls = smem + (ch & 1) * 16384;
    char* const Vls = Kls + 8192;

    // barrier: (a) all waves done reading buf^1, (b) vmcnt(0) inside the
    // barrier drains this chunk's prefetch -> buf ready
    __syncthreads();

    // ---- issue next chunk's staging; flies under this chunk's compute ----
    if (ch < 31) {
      char* const Knx = smem + ((ch + 1) & 1) * 16384;
      gload16(kg + (size_t)(ch + 1) * 4096, Knx + ldb);        // 64 rows x 64c
      gload16(vg + (ch + 1) * 64, Knx + 8192 + ldb);           // 64 s along row
    }

    // ---- QK^T: two 32-s tiles, A = K (rows=s), B = Q (cols=t) ----
    f32x16 lg[2];
#pragma unroll
    for (int st = 0; st < 2; ++st) {
      bf16x8 ka = *(const bf16x8*)(Kls + off[st][0]);
      lg[st] = __builtin_amdgcn_mfma_f32_32x32x16_bf16(ka, qf[0], zv, 0, 0, 0);
#pragma unroll
      for (int kc = 1; kc < 4; ++kc) {
        ka = *(const bf16x8*)(Kls + off[st][kc]);
        lg[st] = __builtin_amdgcn_mfma_f32_32x32x16_bf16(ka, qf[kc], lg[st],
                                                         0, 0, 0);
      }
    }

    // ---- online max: max3-shaped tree + permlane cross-half ----
    float w[11];
#pragma unroll
    for (int i = 0; i < 5; ++i)
      w[i] = fmaxf(fmaxf(lg[0][3 * i], lg[0][3 * i + 1]), lg[0][3 * i + 2]);
    w[5] = fmaxf(fmaxf(lg[0][15], lg[1][0]), lg[1][1]);
#pragma unroll
    for (int i = 0; i < 4; ++i)
      w[6 + i] = fmaxf(fmaxf(lg[1][3 * i + 2], lg[1][3 * i + 3]),
                       lg[1][3 * i + 4]);
    w[10] = fmaxf(lg[1][14], lg[1][15]);
    const float x0 = fmaxf(fmaxf(w[0], w[1]), w[2]);
    const float x1 = fmaxf(fmaxf(w[3], w[4]), w[5]);
    const float x2 = fmaxf(fmaxf(w[6], w[7]), w[8]);
    const float x3 = fmaxf(w[9], w[10]);
    float cm = fmax_x32(fmaxf(fmaxf(x0, x1), fmaxf(x2, x3)));
    if (!__all(cm <= mrun + 8.0f)) {   // deferred rescale, THR=8 (log2)
      const float nm = fmaxf(mrun, cm);
      const float fac = EXP2F(mrun - nm);
      mrun = nm;
      lsum *= fac;
#pragma unroll
      for (int cb = 0; cb < 2; ++cb)
#pragma unroll
        for (int r = 0; r < 16; ++r) acc[cb][r] *= fac;
    }

    // ---- P = exp2(lg - m) in place; pairwise partial sum ----
    float ps = 0.f;
#pragma unroll
    for (int st = 0; st < 2; ++st) {
#pragma unroll
      for (int r = 0; r < 16; ++r) lg[st][r] = EXP2F(lg[st][r] - mrun);
#pragma unroll
      for (int r = 0; r < 8; ++r) ps += lg[st][2 * r] + lg[st][2 * r + 1];
    }
    lsum += ps;

    // ---- pack + redistribute P -> PV fragments pa[ks] (R5-verified) ----
    bf16x8 pa[4];
#pragma unroll
    for (int st = 0; st < 2; ++st) {
#pragma unroll
      for (int kl = 0; kl < 2; ++kl) {
        const unsigned int p0a = pkbf(lg[st][8 * kl + 0], lg[st][8 * kl + 1]);
        const unsigned int p0b = pkbf(lg[st][8 * kl + 2], lg[st][8 * kl + 3]);
        const unsigned int p1a = pkbf(lg[st][8 * kl + 4], lg[st][8 * kl + 5]);
        const unsigned int p1b = pkbf(lg[st][8 * kl + 6], lg[st][8 * kl + 7]);
        const unsigned int sa = hi ? p0a : p1a;
        const unsigned int sb = hi ? p0b : p1b;
        const unsigned int ra = __shfl_xor(sa, 32);
        const unsigned int rb = __shfl_xor(sb, 32);
        union { unsigned int w[4]; bf16x8 v; } u;
        u.w[0] = hi ? ra : p0a;   // k-offsets 0,1
        u.w[1] = hi ? rb : p0b;   // 2,3
        u.w[2] = hi ? p1a : ra;   // 4,5
        u.w[3] = hi ? p1b : rb;   // 6,7
        pa[st * 2 + kl] = u.v;
      }
    }

    // ---- PV: acc[cb] += V * P  (A = V rows=c, B = pa cols=t) ----
#pragma unroll
    for (int cb = 0; cb < 2; ++cb) {
#pragma unroll
      for (int ks = 0; ks < 4; ++ks) {
        const bf16x8 vb = *(const bf16x8*)(Vls + off[cb][ks]);
        acc[cb] = __builtin_amdgcn_mfma_f32_32x32x16_bf16(vb, pa[ks], acc[cb],
                                                          0, 0, 0);
      }
    }
  }

  // ---- epilogue: normalize + store (D: col=t=lane&31, row=c) ----
  const float ls = fadd_x32(lsum);
  const float inv = 1.0f / ls;
#pragma unroll
  for (int cb = 0; cb < 2; ++cb) {
#pragma unroll
    for (int r = 0; r < 16; ++r) {
      const int c = cb * 32 + (r & 3) + 8 * (r >> 2) + 4 * hi;
      out[((size_t)bh * 64 + c) * 2048 + t0w + tl] = acc[cb][r] * inv;
    }
  }
}

extern "C" void kernel_launch(void* const* d_in, const int* in_sizes, int n_in,
                              void* d_out, int out_size, void* d_ws,
                              size_t ws_size, hipStream_t stream) {
  (void)in_sizes; (void)n_in; (void)out_size;
  const float* qkv = (const float*)d_in[0];
  float* out = (float*)d_out;
  const size_t kv_elems = (size_t)64 * 2048 * 64;
  if (ws_size < kv_elems * 2 * sizeof(short)) return;  // need 32 MB scratch
  short* Kt = (short*)d_ws;
  short* Vb = Kt + kv_elems;
  hipLaunchKernelGGL(qkv_prep_kernel, dim3(2048), dim3(256), 0, stream,
                     qkv, Kt, Vb);
  hipLaunchKernelGGL(attn32_kernel, dim3(512), dim3(512), 0, stream,
                     qkv, Kt, Vb, out);
}